// Round 1
// baseline (11.248 us; speedup 1.0000x reference)
//
#include <hip/hip_runtime.h>
#include <hip/hip_bf16.h>

// out[b] = sum_{i=0}^{31} w[i] * x[b]^i  == Horner: (((w31*x + w30)*x + ...)*x + w0)
// Memory-bound: 16 MiB in + 16 MiB out. float4 streaming, grid-stride.

#define DIM 32

__global__ __launch_bounds__(256) void poly_horner_kernel(
    const float* __restrict__ x,
    const float* __restrict__ w,
    float* __restrict__ out,
    int n4)  // number of float4 elements
{
    // Load coefficients (wave-uniform -> scalar loads, L1-resident)
    float c[DIM];
#pragma unroll
    for (int i = 0; i < DIM; ++i) c[i] = w[i];

    const float4* __restrict__ x4 = reinterpret_cast<const float4*>(x);
    float4* __restrict__ out4 = reinterpret_cast<float4*>(out);

    int idx = blockIdx.x * blockDim.x + threadIdx.x;
    int stride = gridDim.x * blockDim.x;

    for (int i = idx; i < n4; i += stride) {
        float4 v = x4[i];
        float4 r;
        r.x = c[DIM - 1];
        r.y = c[DIM - 1];
        r.z = c[DIM - 1];
        r.w = c[DIM - 1];
#pragma unroll
        for (int k = DIM - 2; k >= 0; --k) {
            r.x = fmaf(r.x, v.x, c[k]);
            r.y = fmaf(r.y, v.y, c[k]);
            r.z = fmaf(r.z, v.z, c[k]);
            r.w = fmaf(r.w, v.w, c[k]);
        }
        out4[i] = r;
    }
}

extern "C" void kernel_launch(void* const* d_in, const int* in_sizes, int n_in,
                              void* d_out, int out_size, void* d_ws, size_t ws_size,
                              hipStream_t stream) {
    const float* x = (const float*)d_in[0];
    const float* w = (const float*)d_in[1];
    float* out = (float*)d_out;

    int n = in_sizes[0];          // 4194304
    int n4 = n / 4;               // 1048576 (BATCH divisible by 4)

    const int block = 256;
    int grid = (n4 + block - 1) / block;
    if (grid > 2048) grid = 2048; // grid-stride beyond this

    poly_horner_kernel<<<grid, block, 0, stream>>>(x, w, out, n4);
}